// Round 10
// baseline (303.838 us; speedup 1.0000x reference)
//
#include <hip/hip_runtime.h>
#include <hip/hip_bf16.h>

#define D 128
#define BS 256
#define CHUNK 4096   // edges per partition block
#define CAP 8192     // CSR bucket capacity (entries); actual max ~4700 for this input

typedef __attribute__((ext_vector_type(8))) short short8v;
typedef __attribute__((ext_vector_type(4))) float f32x4;

__device__ __forceinline__ ushort f2bf(float f) {
    uint u = __float_as_uint(f);
    return (ushort)((u + 0x7fffu + ((u >> 16) & 1u)) >> 16);   // RNE
}
__device__ __forceinline__ float bf2f(ushort s) {
    return __uint_as_float(((uint)s) << 16);
}

// ---------------- cvt_all: feats->bf16 (row-major), weights->bf16 transposed, cursor init ----------------

__global__ void cvt_all(const float* __restrict__ feats,
                        const float* __restrict__ Ws0, const float* __restrict__ Wn0,
                        const float* __restrict__ Ws1, const float* __restrict__ Wn1,
                        const float* __restrict__ Ws2, const float* __restrict__ Wn2,
                        ushort* __restrict__ hb, ushort* __restrict__ Wt,
                        int* __restrict__ cursD, int* __restrict__ cursS,
                        int n8, int FB) {
    int tid = threadIdx.x;
    if (blockIdx.x == 0) {
        cursD[tid] = tid * CAP;
        cursS[tid] = tid * CAP;
    }
    if (blockIdx.x < FB) {
        int i = blockIdx.x * 256 + tid;
        if (i >= n8) return;
        const float4* f4 = (const float4*)feats + (size_t)i * 2;
        float4 a = f4[0], b = f4[1];
        uint4 o;
        o.x = (uint)f2bf(a.x) | ((uint)f2bf(a.y) << 16);
        o.y = (uint)f2bf(a.z) | ((uint)f2bf(a.w) << 16);
        o.z = (uint)f2bf(b.x) | ((uint)f2bf(b.y) << 16);
        o.w = (uint)f2bf(b.z) | ((uint)f2bf(b.w) << 16);
        *((uint4*)hb + i) = o;
        return;
    }
    int wb = blockIdx.x - FB;
    int layer = wb >> 7;
    int n = wb & 127;
    int k = tid;
    const float* Ws = (layer == 0) ? Ws0 : (layer == 1) ? Ws1 : Ws2;
    const float* Wn = (layer == 0) ? Wn0 : (layer == 1) ? Wn1 : Wn2;
    float v = (k < 128) ? Ws[k * D + n] : Wn[(k - 128) * D + n];
    Wt[(size_t)layer * 32768 + n * 256 + k] = f2bf(v);
}

// ---------------- partition: LDS hist -> claim bucket ranges -> scatter ----------------
// bufD entry: {(dst&255)<<16 | src, ew}   (requires N <= 65536); bufS entry: {src, ew}

__global__ void partition_kernel(const int* __restrict__ src, const int* __restrict__ dst,
                                 const float* __restrict__ ew,
                                 int* __restrict__ cursD, int* __restrict__ cursS,
                                 int2* __restrict__ bufD, int2* __restrict__ bufS, int E) {
    __shared__ int hD[256], hS[256];
    __shared__ int bD[256], bS[256];
    int tid = threadIdx.x, blk = blockIdx.x;
    hD[tid] = 0; hS[tid] = 0;
    __syncthreads();
    int e0 = blk * CHUNK;
    int e1 = e0 + CHUNK < E ? e0 + CHUNK : E;
    for (int e = e0 + tid; e < e1; e += BS) {
        atomicAdd(&hD[dst[e] >> 8], 1);
        atomicAdd(&hS[src[e] >> 8], 1);
    }
    __syncthreads();
    int cD = hD[tid], cS = hS[tid];
    if (cD > 0) bD[tid] = atomicAdd(&cursD[tid], cD);
    if (cS > 0) bS[tid] = atomicAdd(&cursS[tid], cS);
    __syncthreads();
    for (int e = e0 + tid; e < e1; e += BS) {
        int s = src[e], d = dst[e];
        int w = __float_as_int(ew[e]);
        int pD = atomicAdd(&bD[d >> 8], 1);
        bufD[pD] = make_int2(((d & 255) << 16) | s, w);
        int pS = atomicAdd(&bS[s >> 8], 1);
        bufS[pS] = make_int2(s, w);
    }
}

// ---------------- srcdeg: rs[v] = 1/sqrt(weighted out-degree) ----------------

__global__ void srcdeg_kernel(const int2* __restrict__ bufS, const int* __restrict__ cursS,
                              float* __restrict__ rs, int N) {
    __shared__ float acc[256];
    int tid = threadIdx.x, b = blockIdx.x;
    acc[tid] = 0.f;
    __syncthreads();
    int base = b * CAP;
    int end = cursS[b];
    for (int i = base + tid; i < end; i += BS) {
        int2 v = bufS[i];
        atomicAdd(&acc[v.x & 255], __int_as_float(v.y));
    }
    __syncthreads();
    int node = (b << 8) + tid;
    if (node < N) rs[node] = rsqrtf(acc[tid]);
}

// ---------------- csr: per-bucket counting sort, begend, folded weights ----------------
// w_final = ew * rs[src] * rsqrt(ddst) / in_cnt  (both-norm + mean folded)

__global__ void csr_kernel(const int2* __restrict__ bufD, const int* __restrict__ cursD,
                           const float* __restrict__ rs, int2* __restrict__ begend,
                           int2* __restrict__ csrb, int N) {
    __shared__ int lcnt[256];
    __shared__ float lw[256];
    __shared__ int sc[256];
    int tid = threadIdx.x, b = blockIdx.x;
    lcnt[tid] = 0; lw[tid] = 0.f;
    __syncthreads();
    int base = b * CAP;
    int end = cursD[b];
    for (int i = base + tid; i < end; i += BS) {
        int2 v = bufD[i];
        int l = v.x >> 16;
        atomicAdd(&lcnt[l], 1);
        atomicAdd(&lw[l], __int_as_float(v.y));
    }
    __syncthreads();
    int myc = lcnt[tid];
    float myw = lw[tid];
    sc[tid] = myc;
    __syncthreads();
    for (int off = 1; off < 256; off <<= 1) {
        int t = (tid >= off) ? sc[tid - off] : 0;
        __syncthreads();
        sc[tid] += t;
        __syncthreads();
    }
    int lbase = base + sc[tid] - myc;
    int node = (b << 8) + tid;
    if (node < N) begend[node] = make_int2(lbase, base + sc[tid]);
    lcnt[tid] = lbase;
    lw[tid] = (myc > 0) ? rsqrtf(myw) / (float)myc : 0.f;
    __syncthreads();
    for (int i = base + tid; i < end; i += BS) {
        int2 v = bufD[i];
        int l = v.x >> 16;
        int s = v.x & 0xFFFF;
        float w = __int_as_float(v.y) * rs[s] * lw[l];
        int p = atomicAdd(&lcnt[l], 1);
        csrb[p] = make_int2(s, __float_as_int(w));
    }
}

// ---------------- per-layer FUSED: {aggregate 64 nodes -> nLDS} + {MFMA GEMM} ----------------
// out[v][n] = sum_k h[v][k]*Ws[k][n] + sum_k neigh[v][k]*Wn[k][n] + b[n]
// 512 threads (8 waves). Tile M=64, N=128. Phase A: wave w aggregates nodes
// row0+w*8 .. +7 (8-deep gather ILP) into nLDS[64][132] bf16. Phase B: GEMM
// over K=256: kc 0..3 A=h staged via dbuf LDS; kc 4..7 A-frags direct from nLDS.
// Waves 2(M)x4(N): per-wave 32x32, 2x2 frags of 16x16x32 MFMA.
// A/B frag: lane l, elem j: k = 16*(j>=4) + 4*(l>>4) + (j&3); i/n = l&15.
// C/D frag: reg p: row = 4*(l>>4)+p, col = l&15   [m89-verified]

#define AST2 40   // ushort stride, 80 B rows for As/Bs
#define NST 132   // ushort stride for nLDS, 264 B rows (~2-way on frag reads)

__global__ __launch_bounds__(512, 4) void fused_layer(
    const ushort* __restrict__ hin, const int2* __restrict__ begend,
    const int2* __restrict__ csr, const ushort* __restrict__ Wt,
    const float* __restrict__ bias, ushort* __restrict__ outb,
    float* __restrict__ outf, int N, int relu) {
    __shared__ ushort As[2][64][AST2];
    __shared__ ushort Bs[2][128][AST2];
    __shared__ ushort nLDS[64][NST];

    int tid = threadIdx.x;
    int lane = tid & 63;
    int w = tid >> 6;            // wave 0..7
    int row0 = blockIdx.x * 64;
    int q = lane >> 4, li = lane & 15;

    // ---------- phase A: aggregate 8 nodes per wave into nLDS ----------
    {
        const uint* hs = (const uint*)hin;
        for (int nn = 0; nn < 8; ++nn) {
            int r = w * 8 + nn;
            int node = row0 + r;
            int2 be = (node < N) ? begend[node] : make_int2(0, 0);
            float ax[8], ay[8];
            #pragma unroll
            for (int j = 0; j < 8; ++j) { ax[j] = 0.f; ay[j] = 0.f; }
            int i = be.x;
            for (; i + 8 <= be.y; i += 8) {
                int2 e[8];
                #pragma unroll
                for (int j = 0; j < 8; ++j) e[j] = csr[i + j];
                uint x[8];
                #pragma unroll
                for (int j = 0; j < 8; ++j) x[j] = hs[(size_t)e[j].x * 64 + lane];
                #pragma unroll
                for (int j = 0; j < 8; ++j) {
                    float ww = __int_as_float(e[j].y);
                    ax[j] += ww * bf2f((ushort)x[j]);
                    ay[j] += ww * bf2f((ushort)(x[j] >> 16));
                }
            }
            for (; i < be.y; ++i) {
                int2 e0 = csr[i];
                float ww = __int_as_float(e0.y);
                uint x0 = hs[(size_t)e0.x * 64 + lane];
                ax[0] += ww * bf2f((ushort)x0);
                ay[0] += ww * bf2f((ushort)(x0 >> 16));
            }
            float sx = ((ax[0] + ax[1]) + (ax[2] + ax[3])) + ((ax[4] + ax[5]) + (ax[6] + ax[7]));
            float sy = ((ay[0] + ay[1]) + (ay[2] + ay[3])) + ((ay[4] + ay[5]) + (ay[6] + ay[7]));
            *(uint*)&nLDS[r][2 * lane] = (uint)f2bf(sx) | ((uint)f2bf(sy) << 16);
        }
    }
    __syncthreads();

    // ---------- phase B: GEMM ----------
    int wr = w >> 2, wc = w & 3;          // wave tile: rows wr*32..+31, cols wc*32..+31
    int m0 = wr * 32, n0 = wc * 32;

    // staging coords: B: thread -> Wt row tid>>2 (0..127), 16B chunk c (of 4)
    //                 A (tid<256): row tid>>2 (0..63), chunk c
    int r1 = tid >> 2, c = tid & 3;
    int gra = min(row0 + (tid >> 2), N - 1);   // for A staging (tid<256 uses rows 0..63)

    uint4 sa0, sb0;

    // prologue: stage kc=0
    if (tid < 256) sa0 = *(const uint4*)(hin + (size_t)gra * D + c * 8);
    sb0 = *(const uint4*)(Wt + (size_t)r1 * 256 + c * 8);
    if (tid < 256) *(uint4*)&As[0][tid >> 2][c * 8] = sa0;
    *(uint4*)&Bs[0][r1][c * 8] = sb0;
    __syncthreads();

    f32x4 zero = {0.f, 0.f, 0.f, 0.f};
    f32x4 acc[2][2];
    #pragma unroll
    for (int mf = 0; mf < 2; ++mf)
        #pragma unroll
        for (int nf = 0; nf < 2; ++nf) acc[mf][nf] = zero;

    for (int kc = 0; kc < 8; ++kc) {
        int b = kc & 1;
        // stage next chunk (A only while nc<4; B always)
        if (kc < 7) {
            int nc = kc + 1;
            if (nc < 4 && tid < 256)
                sa0 = *(const uint4*)(hin + (size_t)gra * D + nc * 32 + c * 8);
            sb0 = *(const uint4*)(Wt + (size_t)r1 * 256 + nc * 32 + c * 8);
        }

        union FragU { uint2 u[2]; short8v v; };
        FragU fa[2], fb[2];
        if (kc < 4) {
            #pragma unroll
            for (int mf = 0; mf < 2; ++mf) {
                const ushort* p = &As[b][m0 + mf * 16 + li][0];
                fa[mf].u[0] = *(const uint2*)(p + 4 * q);
                fa[mf].u[1] = *(const uint2*)(p + 16 + 4 * q);
            }
        } else {
            #pragma unroll
            for (int mf = 0; mf < 2; ++mf) {
                const ushort* p = &nLDS[m0 + mf * 16 + li][(kc - 4) * 32 + 4 * q];
                fa[mf].u[0] = *(const uint2*)p;
                fa[mf].u[1] = *(const uint2*)(p + 16);
            }
        }
        #pragma unroll
        for (int nf = 0; nf < 2; ++nf) {
            const ushort* p = &Bs[b][n0 + nf * 16 + li][0];
            fb[nf].u[0] = *(const uint2*)(p + 4 * q);
            fb[nf].u[1] = *(const uint2*)(p + 16 + 4 * q);
        }
        #pragma unroll
        for (int mf = 0; mf < 2; ++mf)
            #pragma unroll
            for (int nf = 0; nf < 2; ++nf)
                acc[mf][nf] = __builtin_amdgcn_mfma_f32_16x16x32_bf16(
                    fa[mf].v, fb[nf].v, acc[mf][nf], 0, 0, 0);

        if (kc < 7) {
            int b2 = b ^ 1;
            int nc = kc + 1;
            if (nc < 4 && tid < 256) *(uint4*)&As[b2][tid >> 2][c * 8] = sa0;
            *(uint4*)&Bs[b2][r1][c * 8] = sb0;
        }
        __syncthreads();
    }

    // ---------- epilogue: + bias, relu, write ----------
    #pragma unroll
    for (int nf = 0; nf < 2; ++nf) {
        int n = n0 + nf * 16 + li;
        float bn = bias[n];
        #pragma unroll
        for (int mf = 0; mf < 2; ++mf) {
            #pragma unroll
            for (int p = 0; p < 4; ++p) {
                int gr = row0 + m0 + mf * 16 + q * 4 + p;
                if (gr >= N) continue;
                float v = acc[mf][nf][p] + bn;
                if (relu) v = fmaxf(v, 0.f);
                if (outf) outf[(size_t)gr * D + n] = v;
                else outb[(size_t)gr * D + n] = f2bf(v);
            }
        }
    }
}

// ---------------- launch ----------------

extern "C" void kernel_launch(void* const* d_in, const int* in_sizes, int n_in,
                              void* d_out, int out_size, void* d_ws, size_t ws_size,
                              hipStream_t stream) {
    const float* feats = (const float*)d_in[0];
    const float* ew    = (const float*)d_in[1];
    const float* Wself[3]  = {(const float*)d_in[2], (const float*)d_in[5], (const float*)d_in[8]};
    const float* Wneigh[3] = {(const float*)d_in[3], (const float*)d_in[6], (const float*)d_in[9]};
    const float* bias[3]   = {(const float*)d_in[4], (const float*)d_in[7], (const float*)d_in[10]};
    const int* src = (const int*)d_in[11];
    const int* dst = (const int*)d_in[12];

    int N = in_sizes[0] / D;     // 50000 (<= 65536 for 16-bit src pack)
    int E = in_sizes[11];        // 850000
    int NB = (N + 255) >> 8;     // 196 buckets
    int EB = (E + CHUNK - 1) / CHUNK;  // 208 partition blocks

    char* ws = (char*)d_ws;
    size_t p = 0;
    auto align256 = [&]() { p = (p + 255) & ~(size_t)255; };

    int* cursD = (int*)(ws + p); p += 256 * 4;             align256();
    int* cursS = (int*)(ws + p); p += 256 * 4;             align256();
    int2* bufD = (int2*)(ws + p); p += (size_t)NB * CAP * 8; align256();
    int2* bufS = (int2*)(ws + p); p += (size_t)NB * CAP * 8; align256();
    int2* csrb = (int2*)(ws + p); p += (size_t)NB * CAP * 8; align256();
    int2* begend = (int2*)(ws + p); p += (size_t)N * 8;    align256();
    float* rs  = (float*)(ws + p); p += (size_t)N * 4;     align256();
    ushort* hA = (ushort*)(ws + p); p += (size_t)N * D * 2; align256();
    ushort* hB = (ushort*)(ws + p); p += (size_t)N * D * 2; align256();
    ushort* Wt = (ushort*)(ws + p); p += (size_t)3 * 128 * 256 * 2; align256();
    (void)ws_size; (void)n_in; (void)out_size;

    int n8 = N * D / 8;
    int FB = (n8 + 255) / 256;   // 3125 feats blocks
    cvt_all<<<FB + 384, 256, 0, stream>>>(feats, Wself[0], Wneigh[0], Wself[1], Wneigh[1],
                                          Wself[2], Wneigh[2], hA, Wt, cursD, cursS, n8, FB);
    partition_kernel<<<EB, BS, 0, stream>>>(src, dst, ew, cursD, cursS, bufD, bufS, E);
    srcdeg_kernel<<<NB, BS, 0, stream>>>(bufS, cursS, rs, N);
    csr_kernel<<<NB, BS, 0, stream>>>(bufD, cursD, rs, begend, csrb, N);

    int gb = (N + 63) / 64;      // 782 fused blocks
    ushort* hin = hA;
    ushort* houts[3] = {hB, hA, nullptr};
    for (int Lr = 0; Lr < 3; ++Lr) {
        fused_layer<<<gb, 512, 0, stream>>>(hin, begend, csrb, Wt + (size_t)Lr * 32768,
                                            bias[Lr], houts[Lr],
                                            (Lr == 2) ? (float*)d_out : nullptr,
                                            N, (Lr < 2) ? 1 : 0);
        hin = houts[Lr];
    }
}

// Round 11
// 224.140 us; speedup vs baseline: 1.3556x; 1.3556x over previous
//
#include <hip/hip_runtime.h>
#include <hip/hip_bf16.h>

#define D 128
#define BS 256
#define CHUNK 4096   // edges per partition block
#define CAP 8192     // CSR bucket capacity (entries); actual max ~4700 for this input

typedef __attribute__((ext_vector_type(8))) short short8v;
typedef __attribute__((ext_vector_type(4))) float f32x4;

__device__ __forceinline__ ushort f2bf(float f) {
    uint u = __float_as_uint(f);
    return (ushort)((u + 0x7fffu + ((u >> 16) & 1u)) >> 16);   // RNE
}
__device__ __forceinline__ float bf2f(ushort s) {
    return __uint_as_float(((uint)s) << 16);
}

// ---------------- cvt_all: feats->bf16 (row-major), weights->bf16 transposed, cursor init ----------------

__global__ void cvt_all(const float* __restrict__ feats,
                        const float* __restrict__ Ws0, const float* __restrict__ Wn0,
                        const float* __restrict__ Ws1, const float* __restrict__ Wn1,
                        const float* __restrict__ Ws2, const float* __restrict__ Wn2,
                        ushort* __restrict__ hb, ushort* __restrict__ Wt,
                        int* __restrict__ cursD, int* __restrict__ cursS,
                        int n8, int FB) {
    int tid = threadIdx.x;
    if (blockIdx.x == 0) {
        cursD[tid] = tid * CAP;
        cursS[tid] = tid * CAP;
    }
    if (blockIdx.x < FB) {
        int i = blockIdx.x * 256 + tid;
        if (i >= n8) return;
        const float4* f4 = (const float4*)feats + (size_t)i * 2;
        float4 a = f4[0], b = f4[1];
        uint4 o;
        o.x = (uint)f2bf(a.x) | ((uint)f2bf(a.y) << 16);
        o.y = (uint)f2bf(a.z) | ((uint)f2bf(a.w) << 16);
        o.z = (uint)f2bf(b.x) | ((uint)f2bf(b.y) << 16);
        o.w = (uint)f2bf(b.z) | ((uint)f2bf(b.w) << 16);
        *((uint4*)hb + i) = o;
        return;
    }
    int wb = blockIdx.x - FB;
    int layer = wb >> 7;
    int n = wb & 127;
    int k = tid;
    const float* Ws = (layer == 0) ? Ws0 : (layer == 1) ? Ws1 : Ws2;
    const float* Wn = (layer == 0) ? Wn0 : (layer == 1) ? Wn1 : Wn2;
    float v = (k < 128) ? Ws[k * D + n] : Wn[(k - 128) * D + n];
    Wt[(size_t)layer * 32768 + n * 256 + k] = f2bf(v);
}

// ---------------- partition: LDS hist -> claim bucket ranges -> scatter ----------------
// bufD entry: {(dst&255)<<16 | src, ew}   (requires N <= 65536); bufS entry: {src, ew}

__global__ void partition_kernel(const int* __restrict__ src, const int* __restrict__ dst,
                                 const float* __restrict__ ew,
                                 int* __restrict__ cursD, int* __restrict__ cursS,
                                 int2* __restrict__ bufD, int2* __restrict__ bufS, int E) {
    __shared__ int hD[256], hS[256];
    __shared__ int bD[256], bS[256];
    int tid = threadIdx.x, blk = blockIdx.x;
    hD[tid] = 0; hS[tid] = 0;
    __syncthreads();
    int e0 = blk * CHUNK;
    int e1 = e0 + CHUNK < E ? e0 + CHUNK : E;
    for (int e = e0 + tid; e < e1; e += BS) {
        atomicAdd(&hD[dst[e] >> 8], 1);
        atomicAdd(&hS[src[e] >> 8], 1);
    }
    __syncthreads();
    int cD = hD[tid], cS = hS[tid];
    if (cD > 0) bD[tid] = atomicAdd(&cursD[tid], cD);
    if (cS > 0) bS[tid] = atomicAdd(&cursS[tid], cS);
    __syncthreads();
    for (int e = e0 + tid; e < e1; e += BS) {
        int s = src[e], d = dst[e];
        int w = __float_as_int(ew[e]);
        int pD = atomicAdd(&bD[d >> 8], 1);
        bufD[pD] = make_int2(((d & 255) << 16) | s, w);
        int pS = atomicAdd(&bS[s >> 8], 1);
        bufS[pS] = make_int2(s, w);
    }
}

// ---------------- srcdeg: rs[v] = 1/sqrt(weighted out-degree) ----------------

__global__ void srcdeg_kernel(const int2* __restrict__ bufS, const int* __restrict__ cursS,
                              float* __restrict__ rs, int N) {
    __shared__ float acc[256];
    int tid = threadIdx.x, b = blockIdx.x;
    acc[tid] = 0.f;
    __syncthreads();
    int base = b * CAP;
    int end = cursS[b];
    for (int i = base + tid; i < end; i += BS) {
        int2 v = bufS[i];
        atomicAdd(&acc[v.x & 255], __int_as_float(v.y));
    }
    __syncthreads();
    int node = (b << 8) + tid;
    if (node < N) rs[node] = rsqrtf(acc[tid]);
}

// ---------------- csr: per-bucket counting sort, begend, folded weights ----------------
// w_final = ew * rs[src] * rsqrt(ddst) / in_cnt  (both-norm + mean folded)

__global__ void csr_kernel(const int2* __restrict__ bufD, const int* __restrict__ cursD,
                           const float* __restrict__ rs, int2* __restrict__ begend,
                           int2* __restrict__ csrb, int N) {
    __shared__ int lcnt[256];
    __shared__ float lw[256];
    __shared__ int sc[256];
    int tid = threadIdx.x, b = blockIdx.x;
    lcnt[tid] = 0; lw[tid] = 0.f;
    __syncthreads();
    int base = b * CAP;
    int end = cursD[b];
    for (int i = base + tid; i < end; i += BS) {
        int2 v = bufD[i];
        int l = v.x >> 16;
        atomicAdd(&lcnt[l], 1);
        atomicAdd(&lw[l], __int_as_float(v.y));
    }
    __syncthreads();
    int myc = lcnt[tid];
    float myw = lw[tid];
    sc[tid] = myc;
    __syncthreads();
    for (int off = 1; off < 256; off <<= 1) {
        int t = (tid >= off) ? sc[tid - off] : 0;
        __syncthreads();
        sc[tid] += t;
        __syncthreads();
    }
    int lbase = base + sc[tid] - myc;
    int node = (b << 8) + tid;
    if (node < N) begend[node] = make_int2(lbase, base + sc[tid]);
    lcnt[tid] = lbase;
    lw[tid] = (myc > 0) ? rsqrtf(myw) / (float)myc : 0.f;
    __syncthreads();
    for (int i = base + tid; i < end; i += BS) {
        int2 v = bufD[i];
        int l = v.x >> 16;
        int s = v.x & 0xFFFF;
        float w = __int_as_float(v.y) * rs[s] * lw[l];
        int p = atomicAdd(&lcnt[l], 1);
        csrb[p] = make_int2(s, __float_as_int(w));
    }
}

// ---------------- per-layer: aggregate (bf16 gather, fp32 accum) ----------------
// R7-verified config: 4-deep unroll, 20 VGPR, ~74% occupancy -> 39.4 us.

__global__ void aggregate_bf(const ushort* __restrict__ h, const int2* __restrict__ begend,
                             const int2* __restrict__ csr, ushort* __restrict__ nb, int N) {
    int node = (blockIdx.x * blockDim.x + threadIdx.x) >> 6;
    int lane = threadIdx.x & 63;
    if (node >= N) return;
    int2 be = begend[node];
    int beg = be.x, end = be.y;
    float ax0 = 0.f, ay0 = 0.f, ax1 = 0.f, ay1 = 0.f;
    float ax2 = 0.f, ay2 = 0.f, ax3 = 0.f, ay3 = 0.f;
    const uint* hs = (const uint*)h;
    int i = beg;
    for (; i + 4 <= end; i += 4) {
        int2 e0 = csr[i], e1 = csr[i + 1], e2 = csr[i + 2], e3 = csr[i + 3];
        float w0 = __int_as_float(e0.y), w1 = __int_as_float(e1.y);
        float w2 = __int_as_float(e2.y), w3 = __int_as_float(e3.y);
        uint x0 = hs[(size_t)e0.x * 64 + lane];
        uint x1 = hs[(size_t)e1.x * 64 + lane];
        uint x2 = hs[(size_t)e2.x * 64 + lane];
        uint x3 = hs[(size_t)e3.x * 64 + lane];
        ax0 += w0 * bf2f((ushort)x0); ay0 += w0 * bf2f((ushort)(x0 >> 16));
        ax1 += w1 * bf2f((ushort)x1); ay1 += w1 * bf2f((ushort)(x1 >> 16));
        ax2 += w2 * bf2f((ushort)x2); ay2 += w2 * bf2f((ushort)(x2 >> 16));
        ax3 += w3 * bf2f((ushort)x3); ay3 += w3 * bf2f((ushort)(x3 >> 16));
    }
    for (; i < end; ++i) {
        int2 e0 = csr[i];
        float w0 = __int_as_float(e0.y);
        uint x0 = hs[(size_t)e0.x * 64 + lane];
        ax0 += w0 * bf2f((ushort)x0); ay0 += w0 * bf2f((ushort)(x0 >> 16));
    }
    float rx = (ax0 + ax1) + (ax2 + ax3);
    float ry = (ay0 + ay1) + (ay2 + ay3);
    uint o = (uint)f2bf(rx) | ((uint)f2bf(ry) << 16);
    ((uint*)nb)[(size_t)node * 64 + lane] = o;
}

// ---------------- per-layer: MFMA GEMM, 64x128 tile (R9-verified config) ----------------
// out[v][n] = sum_{k<256} A[v][k] * Wt[n][k] + b[n]   (A = [h | neigh] bf16 row-major)
// 64(M)x128(N) tile, 4 waves (2x2), 32x64 per wave, 16x16x32 MFMA, dbuf LDS.
// A/B frag: lane l, elem j: k = 16*(j>=4) + 4*(l>>4) + (j&3); i/n = l&15.
// C/D frag: reg p: row = 4*(l>>4)+p, col = l&15   [m89-verified]

#define AST2 40  // ushort stride per LDS row (80 B): 2-way max on frag reads

__global__ __launch_bounds__(256, 4) void mfma_gemm(
    const ushort* __restrict__ A1, const ushort* __restrict__ A2,
    const ushort* __restrict__ Wt, const float* __restrict__ bias,
    ushort* __restrict__ outb, float* __restrict__ outf, int N, int relu) {
    __shared__ ushort As[2][64][AST2];
    __shared__ ushort Bs[2][128][AST2];

    int tid = threadIdx.x;
    int lane = tid & 63;
    int w = tid >> 6;
    int m0 = (w >> 1) * 32, n0 = (w & 1) * 64;
    int row0 = blockIdx.x * 64;
    int q = lane >> 4, li = lane & 15;

    int r1 = tid >> 2, c = tid & 3;
    int gr1 = min(row0 + r1, N - 1);

    uint4 sa0, sb0, sb1;

    // prologue: stage kc=0
    sa0 = *(const uint4*)(A1 + (size_t)gr1 * D + c * 8);
    sb0 = *(const uint4*)(Wt + (size_t)r1 * 256 + c * 8);
    sb1 = *(const uint4*)(Wt + (size_t)(r1 + 64) * 256 + c * 8);
    *(uint4*)&As[0][r1][c * 8] = sa0;
    *(uint4*)&Bs[0][r1][c * 8] = sb0;
    *(uint4*)&Bs[0][r1 + 64][c * 8] = sb1;
    __syncthreads();

    f32x4 zero = {0.f, 0.f, 0.f, 0.f};
    f32x4 acc[2][4];
    #pragma unroll
    for (int mf = 0; mf < 2; ++mf)
        #pragma unroll
        for (int nf = 0; nf < 4; ++nf) acc[mf][nf] = zero;

    for (int kc = 0; kc < 8; ++kc) {
        int b = kc & 1;
        if (kc < 7) {
            int nc = kc + 1;
            const ushort* Ak = ((nc < 4) ? A1 : A2) + (nc & 3) * 32;
            sa0 = *(const uint4*)(Ak + (size_t)gr1 * D + c * 8);
            const ushort* Wk = Wt + nc * 32;
            sb0 = *(const uint4*)(Wk + (size_t)r1 * 256 + c * 8);
            sb1 = *(const uint4*)(Wk + (size_t)(r1 + 64) * 256 + c * 8);
        }

        union FragU { uint2 u[2]; short8v v; };
        FragU fa[2], fb[4];
        #pragma unroll
        for (int mf = 0; mf < 2; ++mf) {
            const ushort* p = &As[b][m0 + mf * 16 + li][0];
            fa[mf].u[0] = *(const uint2*)(p + 4 * q);
            fa[mf].u[1] = *(const uint2*)(p + 16 + 4 * q);
        }
        #pragma unroll
        for (int nf = 0; nf < 4; ++nf) {
            const ushort* p = &Bs[b][n0 + nf * 16 + li][0];
            fb[nf].u[0] = *(const uint2*)(p + 4 * q);
            fb[nf].u[1] = *(const uint2*)(p + 16 + 4 * q);
        }
        #pragma unroll
        for (int mf = 0; mf < 2; ++mf)
            #pragma unroll
            for (int nf = 0; nf < 4; ++nf)
                acc[mf][nf] = __builtin_amdgcn_mfma_f32_16x16x32_bf16(
                    fa[mf].v, fb[nf].v, acc[mf][nf], 0, 0, 0);

        if (kc < 7) {
            int b2 = b ^ 1;
            *(uint4*)&As[b2][r1][c * 8] = sa0;
            *(uint4*)&Bs[b2][r1][c * 8] = sb0;
            *(uint4*)&Bs[b2][r1 + 64][c * 8] = sb1;
        }
        __syncthreads();
    }

    #pragma unroll
    for (int nf = 0; nf < 4; ++nf) {
        int n = n0 + nf * 16 + li;
        float bn = bias[n];
        #pragma unroll
        for (int mf = 0; mf < 2; ++mf) {
            #pragma unroll
            for (int p = 0; p < 4; ++p) {
                int gr = row0 + m0 + mf * 16 + q * 4 + p;
                if (gr >= N) continue;
                float v = acc[mf][nf][p] + bn;
                if (relu) v = fmaxf(v, 0.f);
                if (outf) outf[(size_t)gr * D + n] = v;
                else outb[(size_t)gr * D + n] = f2bf(v);
            }
        }
    }
}

// ---------------- launch ----------------

extern "C" void kernel_launch(void* const* d_in, const int* in_sizes, int n_in,
                              void* d_out, int out_size, void* d_ws, size_t ws_size,
                              hipStream_t stream) {
    const float* feats = (const float*)d_in[0];
    const float* ew    = (const float*)d_in[1];
    const float* Wself[3]  = {(const float*)d_in[2], (const float*)d_in[5], (const float*)d_in[8]};
    const float* Wneigh[3] = {(const float*)d_in[3], (const float*)d_in[6], (const float*)d_in[9]};
    const float* bias[3]   = {(const float*)d_in[4], (const float*)d_in[7], (const float*)d_in[10]};
    const int* src = (const int*)d_in[11];
    const int* dst = (const int*)d_in[12];

    int N = in_sizes[0] / D;     // 50000 (<= 65536 for 16-bit src pack)
    int E = in_sizes[11];        // 850000
    int NB = (N + 255) >> 8;     // 196 buckets
    int EB = (E + CHUNK - 1) / CHUNK;  // 208 partition blocks

    char* ws = (char*)d_ws;
    size_t p = 0;
    auto align256 = [&]() { p = (p + 255) & ~(size_t)255; };

    int* cursD = (int*)(ws + p); p += 256 * 4;             align256();
    int* cursS = (int*)(ws + p); p += 256 * 4;             align256();
    int2* bufD = (int2*)(ws + p); p += (size_t)NB * CAP * 8; align256();
    int2* bufS = (int2*)(ws + p); p += (size_t)NB * CAP * 8; align256();
    int2* csrb = (int2*)(ws + p); p += (size_t)NB * CAP * 8; align256();
    int2* begend = (int2*)(ws + p); p += (size_t)N * 8;    align256();
    float* rs  = (float*)(ws + p); p += (size_t)N * 4;     align256();
    ushort* hA = (ushort*)(ws + p); p += (size_t)N * D * 2; align256();
    ushort* hB = (ushort*)(ws + p); p += (size_t)N * D * 2; align256();
    ushort* nbuf = (ushort*)(ws + p); p += (size_t)N * D * 2; align256();
    ushort* Wt = (ushort*)(ws + p); p += (size_t)3 * 128 * 256 * 2; align256();
    (void)ws_size; (void)n_in; (void)out_size;

    int n8 = N * D / 8;
    int FB = (n8 + 255) / 256;   // 3125 feats blocks
    cvt_all<<<FB + 384, 256, 0, stream>>>(feats, Wself[0], Wneigh[0], Wself[1], Wneigh[1],
                                          Wself[2], Wneigh[2], hA, Wt, cursD, cursS, n8, FB);
    partition_kernel<<<EB, BS, 0, stream>>>(src, dst, ew, cursD, cursS, bufD, bufS, E);
    srcdeg_kernel<<<NB, BS, 0, stream>>>(bufS, cursS, rs, N);
    csr_kernel<<<NB, BS, 0, stream>>>(bufD, cursD, rs, begend, csrb, N);

    int gb = (N + 63) / 64;      // 782 gemm blocks
    ushort* hin = hA;
    ushort* houts[3] = {hB, hA, nullptr};
    for (int Lr = 0; Lr < 3; ++Lr) {
        aggregate_bf<<<(N + 3) / 4, 256, 0, stream>>>(hin, begend, csrb, nbuf, N);
        mfma_gemm<<<gb, 256, 0, stream>>>(hin, nbuf, Wt + (size_t)Lr * 32768, bias[Lr],
                                          houts[Lr], (Lr == 2) ? (float*)d_out : nullptr,
                                          N, (Lr < 2) ? 1 : 0);
        hin = houts[Lr];
    }
}